// Round 3
// baseline (568.123 us; speedup 1.0000x reference)
//
#include <hip/hip_runtime.h>
#include <stdint.h>

typedef unsigned short u16;
typedef __bf16 bf16x8 __attribute__((ext_vector_type(8)));
typedef float f32x4 __attribute__((ext_vector_type(4)));

typedef const __attribute__((address_space(1))) uint32_t* gu32p;
typedef __attribute__((address_space(3))) uint32_t* lu32p;
#define GLOAD_LDS16(g, l) \
  __builtin_amdgcn_global_load_lds((gu32p)(const void*)(g), (lu32p)(void*)(l), 16, 0, 0)

static __device__ __forceinline__ u16 f2bf(float f) {
  uint32_t u = __builtin_bit_cast(uint32_t, f);
  return (u16)((u + 0x7FFFu + ((u >> 16) & 1u)) >> 16);
}
static __device__ __forceinline__ float bf2f(u16 h) {
  uint32_t u = ((uint32_t)h) << 16;
  return __builtin_bit_cast(float, u);
}

// ---------------- fp32 -> bf16 conversion ----------------
__global__ __launch_bounds__(256) void k_f32_to_bf16(const float* __restrict__ in,
                                                     u16* __restrict__ out, int n) {
  int i = (blockIdx.x * 256 + threadIdx.x) * 4;
  if (i + 3 < n) {
    const float4 v = *(const float4*)&in[i];
    ushort4 o;
    o.x = f2bf(v.x); o.y = f2bf(v.y); o.z = f2bf(v.z); o.w = f2bf(v.w);
    *(ushort4*)&out[i] = o;
  }
}

// ---------------- 256x256 MFMA tile core, pipelined (T3 minimal) ----------------
// A: M x K row-major; Bt: N x K row-major. 512 threads = 8 waves (2M x 4N);
// per-wave 128x64 output = acc[8][4] of 16x16 frags. BK=32.
// LDS: 2 dbuf x (A 256x32 + B 256x32) bf16 = 64 KiB, linear layout
// (64B rows -> row index feeds bank bits -> uniform 8 words/bank on ds_read_b128).
// Pipeline per K-step: stage tile t+1 (4 global_load_lds) -> ds_read frags ->
// 32 MFMA (setprio 1) -> vmcnt(0) (shadowed by compute) -> one raw s_barrier.
__device__ __forceinline__ void gemm256(const u16* __restrict__ A, const u16* __restrict__ Bt,
                                        int lda, int ldb, long row0, long col0,
                                        int kbeg, int kend, u16* smem, f32x4 acc[8][4]) {
  const int tid = threadIdx.x;
  const int l = tid & 63;
  const int wid = tid >> 6;
  const int wm = wid >> 2, wn = wid & 3;
  // staging: per wave 4 chunks (A half0/half1, B half0/half1), chunk = 16 rows x 32 cols
  const int crow = wid * 16 + (l >> 2);          // row within a 128-row half
  const int ccol = (l & 3) * 8;                  // col (elems)
  const u16* ga0 = &A[(row0 + crow) * (long)lda + ccol];
  const u16* ga1 = &A[(row0 + 128 + crow) * (long)lda + ccol];
  const u16* gb0 = &Bt[(col0 + crow) * (long)ldb + ccol];
  const u16* gb1 = &Bt[(col0 + 128 + crow) * (long)ldb + ccol];
  const int ldsoff = wid * 512;                  // wave-uniform chunk base (elems)
  const int lr = l & 15, lk = (l >> 4) * 8;
  const int NT = (kend - kbeg) >> 5;

  { // prologue: stage tile 0 into dbuf 0
    u16* d0 = smem + ldsoff;
    GLOAD_LDS16(ga0 + kbeg, d0);
    GLOAD_LDS16(ga1 + kbeg, d0 + 4096);
    GLOAD_LDS16(gb0 + kbeg, d0 + 8192);
    GLOAD_LDS16(gb1 + kbeg, d0 + 12288);
  }
  asm volatile("s_waitcnt vmcnt(0)" ::: "memory");
  __builtin_amdgcn_s_barrier();
  __builtin_amdgcn_sched_barrier(0);

  for (int t = 0; t < NT; ++t) {
    const int d = (t & 1) * 16384;
    if (t + 1 < NT) {                            // stage tile t+1 into other dbuf
      const int k1 = kbeg + (t + 1) * 32;
      u16* dn = smem + (((t + 1) & 1) * 16384 + ldsoff);
      GLOAD_LDS16(ga0 + k1, dn);
      GLOAD_LDS16(ga1 + k1, dn + 4096);
      GLOAD_LDS16(gb0 + k1, dn + 8192);
      GLOAD_LDS16(gb1 + k1, dn + 12288);
    }
    bf16x8 af[8], bv[4];
#pragma unroll
    for (int mf = 0; mf < 8; ++mf)
      af[mf] = *(const bf16x8*)&smem[d + (wm * 128 + mf * 16 + lr) * 32 + lk];
#pragma unroll
    for (int nf = 0; nf < 4; ++nf)
      bv[nf] = *(const bf16x8*)&smem[d + 8192 + (wn * 64 + nf * 16 + lr) * 32 + lk];
    __builtin_amdgcn_s_setprio(1);
#pragma unroll
    for (int mf = 0; mf < 8; ++mf)
#pragma unroll
      for (int nf = 0; nf < 4; ++nf)
        acc[mf][nf] = __builtin_amdgcn_mfma_f32_16x16x32_bf16(af[mf], bv[nf], acc[mf][nf], 0, 0, 0);
    __builtin_amdgcn_s_setprio(0);
    asm volatile("s_waitcnt vmcnt(0)" ::: "memory");   // drains t+1 stage; shadowed by MFMAs
    __builtin_amdgcn_s_barrier();
    __builtin_amdgcn_sched_barrier(0);
  }
}

#define EPI_VARS256                                \
  const int l = threadIdx.x & 63;                  \
  const int wid = threadIdx.x >> 6;                \
  const int wm = wid >> 2, wn = wid & 3;           \
  const int mrow = (l >> 4) * 4, ncol = l & 15;

// ---------------- QKV projection (input + context merged) ----------------
__global__ __launch_bounds__(512, 2) void k_gemm_qkv256(
    const u16* __restrict__ XIN, const u16* __restrict__ XCTX,
    const u16* __restrict__ WQI, const u16* __restrict__ WQC,
    const float* __restrict__ bqi, const float* __restrict__ bqc,
    u16* __restrict__ qb, u16* __restrict__ kb, u16* __restrict__ vt) {
  __shared__ u16 smem[32768];
  f32x4 acc[8][4] = {};
  const bool isCtx = blockIdx.x >= 32;
  const u16* X = isCtx ? XCTX : XIN;
  const u16* W = isCtx ? WQC : WQI;
  const float* bias = isCtx ? bqc : bqi;
  const int seg_start = isCtx ? 0 : 512;
  long row0 = (long)(isCtx ? blockIdx.x - 32 : blockIdx.x) * 256;
  long col0 = (long)blockIdx.y * 256;
  gemm256(X, W, 1024, 1024, row0, col0, 0, 1024, smem, acc);
  EPI_VARS256
#pragma unroll
  for (int mf = 0; mf < 8; ++mf)
#pragma unroll
    for (int nf = 0; nf < 4; ++nf)
#pragma unroll
      for (int r = 0; r < 4; ++r) {
        int m = (int)row0 + wm * 128 + mf * 16 + mrow + r;
        int n = (int)col0 + wn * 64 + nf * 16 + ncol;
        float v = acc[mf][nf][r] + bias[n];
        int b, s;
        if (isCtx) { b = m >> 9; s = m & 511; } else { b = m >> 12; s = m & 4095; }
        long grow = (long)b * 4608 + seg_start + s;
        if (n < 1024)      qb[grow * 1024 + n] = f2bf(v);
        else if (n < 2048) kb[grow * 1024 + (n - 1024)] = f2bf(v);
        else               vt[((long)b * 1024 + (n - 2048)) * 4608 + seg_start + s] = f2bf(v);
      }
}

// ---------------- RMSNorm + RoPE (in-place on q_buf / k_buf) ----------------
__global__ __launch_bounds__(256) void k_normrope(u16* __restrict__ qb, u16* __restrict__ kb,
                                                  const float* __restrict__ qsi, const float* __restrict__ ksi,
                                                  const float* __restrict__ qsc, const float* __restrict__ ksc) {
  __shared__ float sm[4];
  const int row = blockIdx.x;    // 0..9215  (b*4608 + n)
  const int which = blockIdx.y;  // 0 = q, 1 = k
  const int n = row % 4608;
  u16* buf = which ? kb : qb;
  const float* scale = which ? (n < 512 ? ksc : ksi) : (n < 512 ? qsc : qsi);
  u16* rp = buf + (long)row * 1024;
  const int t = threadIdx.x;
  float x[4];
  int idx[4];
  float ss = 0.f;
#pragma unroll
  for (int i = 0; i < 2; ++i) {
    int p = t + i * 256;                 // pair index 0..511
    int h = p >> 5, j = p & 31;          // head, rot index
    int e1 = h * 64 + j;
    idx[2 * i] = e1; idx[2 * i + 1] = e1 + 32;
    float a = bf2f(rp[e1]), b = bf2f(rp[e1 + 32]);
    x[2 * i] = a; x[2 * i + 1] = b;
    ss += a * a + b * b;
  }
#pragma unroll
  for (int o = 32; o; o >>= 1) ss += __shfl_xor(ss, o, 64);
  if ((t & 63) == 0) sm[t >> 6] = ss;
  __syncthreads();
  ss = sm[0] + sm[1] + sm[2] + sm[3];
  const float rr = rsqrtf(ss * (1.0f / 1024.0f) + 1e-6f);
#pragma unroll
  for (int i = 0; i < 2; ++i) {
    int p = t + i * 256;
    int j = p & 31;
    float x1 = x[2 * i] * rr * scale[idx[2 * i]];
    float x2 = x[2 * i + 1] * rr * scale[idx[2 * i + 1]];
    float freq = exp2f((float)j * (-13.287712379549449f / 32.0f)); // 10000^(-j/32)
    float ang = (float)n * freq;
    float sn, cs;
    sincosf(ang, &sn, &cs);
    rp[idx[2 * i]]     = f2bf(x1 * cs - x2 * sn);
    rp[idx[2 * i + 1]] = f2bf(x2 * cs + x1 * sn);
  }
}

// ---------------- S = (Q @ K^T) * 0.125  (fp32 out) ----------------
__global__ __launch_bounds__(512, 2) void k_gemm_s256(const u16* __restrict__ Q, const u16* __restrict__ Kb,
                                                      float* __restrict__ S) {
  __shared__ u16 smem[32768];
  f32x4 acc[8][4] = {};
  long row0 = (long)blockIdx.x * 256;
  long col0 = (long)blockIdx.y * 256;
  gemm256(Q, Kb, 1024, 1024, row0, col0, 0, 1024, smem, acc);
  EPI_VARS256
#pragma unroll
  for (int mf = 0; mf < 8; ++mf)
#pragma unroll
    for (int nf = 0; nf < 4; ++nf)
#pragma unroll
      for (int r = 0; r < 4; ++r) {
        long m = row0 + wm * 128 + mf * 16 + mrow + r;
        long n = col0 + wn * 64 + nf * 16 + ncol;
        S[m * 4608 + n] = acc[mf][nf][r] * 0.125f;
      }
}

// ---------------- row softmax: P = softmax(S row) as bf16 ----------------
__global__ __launch_bounds__(256) void k_softmax(const float* __restrict__ S, u16* __restrict__ P) {
  __shared__ float sm[4];
  const long row = blockIdx.x;
  const float* sr = S + row * 4608;
  const int t = threadIdx.x;
  float v[18];
  float mx = -3.4e38f;
#pragma unroll
  for (int i = 0; i < 18; ++i) { v[i] = sr[i * 256 + t]; mx = fmaxf(mx, v[i]); }
#pragma unroll
  for (int o = 32; o; o >>= 1) mx = fmaxf(mx, __shfl_xor(mx, o, 64));
  if ((t & 63) == 0) sm[t >> 6] = mx;
  __syncthreads();
  mx = fmaxf(fmaxf(sm[0], sm[1]), fmaxf(sm[2], sm[3]));
  __syncthreads();
  float sum = 0.f;
#pragma unroll
  for (int i = 0; i < 18; ++i) { v[i] = __expf(v[i] - mx); sum += v[i]; }
#pragma unroll
  for (int o = 32; o; o >>= 1) sum += __shfl_xor(sum, o, 64);
  if ((t & 63) == 0) sm[t >> 6] = sum;
  __syncthreads();
  sum = sm[0] + sm[1] + sm[2] + sm[3];
  const float inv = 1.0f / sum;
  u16* pr = P + row * 4608;
#pragma unroll
  for (int i = 0; i < 18; ++i) pr[i * 256 + t] = f2bf(v[i] * inv);
}

// ---------------- O partials = P @ V (split-K over z), fp32 out ----------------
__global__ __launch_bounds__(512, 2) void k_gemm_o256(const u16* __restrict__ P, const u16* __restrict__ VT,
                                                      float* __restrict__ OP) {
  __shared__ u16 smem[32768];
  f32x4 acc[8][4] = {};
  long row0 = (long)blockIdx.x * 256;
  long col0 = (long)blockIdx.y * 256;
  const int kc = blockIdx.z;           // 0..3, K chunk of 1152
  gemm256(P, VT, 4608, 4608, row0, col0, kc * 1152, (kc + 1) * 1152, smem, acc);
  float* op = OP + (long)kc * 4608 * 1024;
  EPI_VARS256
#pragma unroll
  for (int mf = 0; mf < 8; ++mf)
#pragma unroll
    for (int nf = 0; nf < 4; ++nf)
#pragma unroll
      for (int r = 0; r < 4; ++r) {
        long m = row0 + wm * 128 + mf * 16 + mrow + r;
        long n = col0 + wn * 64 + nf * 16 + ncol;
        op[m * 1024 + n] = acc[mf][nf][r];
      }
}

// ---------------- reduce 4 fp32 partials -> bf16 AO ----------------
__global__ __launch_bounds__(256) void k_reduce4(const float* __restrict__ OP, u16* __restrict__ AO) {
  const long st = 4608L * 1024;
  long i = ((long)blockIdx.x * 256 + threadIdx.x) * 4;
  float4 a = *(const float4*)&OP[i];
  float4 b = *(const float4*)&OP[i + st];
  float4 c = *(const float4*)&OP[i + 2 * st];
  float4 d = *(const float4*)&OP[i + 3 * st];
  ushort4 o;
  o.x = f2bf(a.x + b.x + c.x + d.x);
  o.y = f2bf(a.y + b.y + c.y + d.y);
  o.z = f2bf(a.z + b.z + c.z + d.z);
  o.w = f2bf(a.w + b.w + c.w + d.w);
  *(ushort4*)&AO[i] = o;
}

// ---------------- merged output projections: out = AO @ W^T + b (fp32 out) ----------------
__global__ __launch_bounds__(512, 2) void k_gemm_out256(const u16* __restrict__ AO,
                                                        const u16* __restrict__ WOI, const u16* __restrict__ WOC,
                                                        const float* __restrict__ boi, const float* __restrict__ boc,
                                                        float* __restrict__ out) {
  __shared__ u16 smem[32768];
  f32x4 acc[8][4] = {};
  long row0 = (long)blockIdx.x * 256;      // global row in [0,9216)
  long col0 = (long)blockIdx.y * 256;
  int b = (int)(row0 / 4608);
  int s0 = (int)(row0 % 4608);
  const bool ctx = s0 < 512;               // 512 % 256 == 0 -> uniform per block
  const u16* W = ctx ? WOC : WOI;
  const float* bias = ctx ? boc : boi;
  float* ob = ctx ? out + 8388608 + ((long)b * 512 + s0) * 1024
                  : out + ((long)b * 4096 + (s0 - 512)) * 1024;
  gemm256(AO, W, 1024, 1024, row0, col0, 0, 1024, smem, acc);
  EPI_VARS256
#pragma unroll
  for (int mf = 0; mf < 8; ++mf)
#pragma unroll
    for (int nf = 0; nf < 4; ++nf)
#pragma unroll
      for (int r = 0; r < 4; ++r) {
        long m = wm * 128 + mf * 16 + mrow + r;        // local row within tile
        long n = col0 + wn * 64 + nf * 16 + ncol;
        ob[m * 1024 + n] = acc[mf][nf][r] + bias[n];
      }
}

// ---------------- launch ----------------
extern "C" void kernel_launch(void* const* d_in, const int* in_sizes, int n_in,
                              void* d_out, int out_size, void* d_ws, size_t ws_size,
                              hipStream_t stream) {
  const float* input   = (const float*)d_in[0];
  const float* context = (const float*)d_in[1];
  const float* Wqi     = (const float*)d_in[2];
  const float* bqi     = (const float*)d_in[3];
  const float* Wqc     = (const float*)d_in[4];
  const float* bqc     = (const float*)d_in[5];
  const float* qsi     = (const float*)d_in[6];
  const float* ksi     = (const float*)d_in[7];
  const float* qsc     = (const float*)d_in[8];
  const float* ksc     = (const float*)d_in[9];
  const float* Woi     = (const float*)d_in[10];
  const float* boi     = (const float*)d_in[11];
  const float* Woc     = (const float*)d_in[12];
  const float* boc     = (const float*)d_in[13];
  float* out = (float*)d_out;

  uint8_t* ws = (uint8_t*)d_ws;
  // workspace layout (bytes)
  u16* XIN  = (u16*)(ws + 0);            // 2*4096*1024 bf16       = 16,777,216
  u16* XCTX = (u16*)(ws + 16777216);     // 2*512*1024             =  2,097,152
  u16* WQI  = (u16*)(ws + 18874368);     // 3072*1024              =  6,291,456
  u16* WQC  = (u16*)(ws + 25165824);     // 3072*1024              =  6,291,456
  u16* WOI  = (u16*)(ws + 31457280);     // 1024*1024              =  2,097,152
  u16* WOC  = (u16*)(ws + 33554432);     // 1024*1024              =  2,097,152
  u16* QB   = (u16*)(ws + 35651584);     // 2*4608*1024            = 18,874,368
  u16* KB   = (u16*)(ws + 54525952);     // 2*4608*1024            = 18,874,368
  u16* VT   = (u16*)(ws + 73400320);     // 2*1024*4608            = 18,874,368
  u16* AO   = (u16*)(ws + 92274688);     // 2*4608*1024            = 18,874,368
  float* S32 = (float*)(ws + 111149056); // 4608*4608 fp32 (per-batch; also 4x fp32 O-partials) = 84,934,656
  u16* PB   = (u16*)(ws + 196083712);    // 4608*4608 bf16 (per-batch, reused) = 42,467,328
  // total = 238,551,040 bytes

  // fp32 -> bf16 conversions
  k_f32_to_bf16<<<dim3(8192), 256, 0, stream>>>(input, XIN, 2 * 4096 * 1024);
  k_f32_to_bf16<<<dim3(1024), 256, 0, stream>>>(context, XCTX, 2 * 512 * 1024);
  k_f32_to_bf16<<<dim3(3072), 256, 0, stream>>>(Wqi, WQI, 3072 * 1024);
  k_f32_to_bf16<<<dim3(3072), 256, 0, stream>>>(Wqc, WQC, 3072 * 1024);
  k_f32_to_bf16<<<dim3(1024), 256, 0, stream>>>(Woi, WOI, 1024 * 1024);
  k_f32_to_bf16<<<dim3(1024), 256, 0, stream>>>(Woc, WOC, 1024 * 1024);

  // QKV projections, input + context in one launch (blocks 0..31 input, 32..35 ctx)
  k_gemm_qkv256<<<dim3(36, 12), 512, 0, stream>>>(XIN, XCTX, WQI, WQC, bqi, bqc, QB, KB, VT);

  // RMSNorm + RoPE in place on q,k
  k_normrope<<<dim3(9216, 2), 256, 0, stream>>>(QB, KB, qsi, ksi, qsc, ksc);

  // attention, one batch at a time (S/P buffers reused; O-partials alias S32)
  for (int b = 0; b < 2; ++b) {
    const u16* Qb  = QB + (long)b * 4608 * 1024;
    const u16* Kbp = KB + (long)b * 4608 * 1024;
    const u16* VTb = VT + (long)b * 1024 * 4608;
    u16* AOb = AO + (long)b * 4608 * 1024;
    k_gemm_s256<<<dim3(18, 18), 512, 0, stream>>>(Qb, Kbp, S32);
    k_softmax<<<dim3(4608), 256, 0, stream>>>(S32, PB);
    k_gemm_o256<<<dim3(18, 4, 4), 512, 0, stream>>>(PB, VTb, (float*)S32);
    k_reduce4<<<dim3(4608), 256, 0, stream>>>((const float*)S32, AOb);
  }

  // merged output projections
  k_gemm_out256<<<dim3(36, 4), 512, 0, stream>>>(AO, WOI, WOC, boi, boc, out);
}

// Round 4
// 480.669 us; speedup vs baseline: 1.1819x; 1.1819x over previous
//
#include <hip/hip_runtime.h>
#include <stdint.h>

typedef unsigned short u16;
typedef __bf16 bf16x8 __attribute__((ext_vector_type(8)));
typedef float f32x4 __attribute__((ext_vector_type(4)));

typedef const __attribute__((address_space(1))) uint32_t* gu32p;
typedef __attribute__((address_space(3))) uint32_t* lu32p;
#define GLOAD_LDS16(g, l) \
  __builtin_amdgcn_global_load_lds((gu32p)(const void*)(g), (lu32p)(void*)(l), 16, 0, 0)

static __device__ __forceinline__ u16 f2bf(float f) {
  uint32_t u = __builtin_bit_cast(uint32_t, f);
  return (u16)((u + 0x7FFFu + ((u >> 16) & 1u)) >> 16);
}
static __device__ __forceinline__ float bf2f(u16 h) {
  uint32_t u = ((uint32_t)h) << 16;
  return __builtin_bit_cast(float, u);
}

// ---------------- fp32 -> bf16 conversion ----------------
__global__ __launch_bounds__(256) void k_f32_to_bf16(const float* __restrict__ in,
                                                     u16* __restrict__ out, int n) {
  int i = (blockIdx.x * 256 + threadIdx.x) * 4;
  if (i + 3 < n) {
    const float4 v = *(const float4*)&in[i];
    ushort4 o;
    o.x = f2bf(v.x); o.y = f2bf(v.y); o.z = f2bf(v.z); o.w = f2bf(v.w);
    *(ushort4*)&out[i] = o;
  }
}

// ---------------- 128x128 MFMA tile core, BK=64, swizzled, 2-dbuf ----------------
// A: M x K row-major; Bt: N x K row-major. 256 threads = 4 waves (2M x 2N);
// per-wave 64x64 output = acc[4][4]. LDS: 2 dbuf x (A[128][64] + B[128][64]) = 64 KiB.
// Swizzle: LDS 16B-slot L of row r holds global 16B-slot L^(r&7) (involution).
//   - staging: linear LDS write (global_load_lds), source col pre-swizzled
//   - ds_read: slot (s*4+kg) ^ (lr&7)  -> every bank exactly 8 words (b128 minimum)
// Per K-tile: [stage A(t+1)] s=0 frags + 16 MFMA, [stage B(t+1)] s=1 frags + 16 MFMA,
// then vmcnt(0) + one s_barrier. Load->wait window ~= one full tile of compute.
__device__ __forceinline__ void gemm_bk64(const u16* __restrict__ A, const u16* __restrict__ Bt,
                                          int lda, int ldb, long row0, long col0,
                                          int kbeg, int kend, u16* smem, f32x4 acc[4][4]) {
  const int tid = threadIdx.x;
  const int l = tid & 63;
  const int w = tid >> 6;
  const int wm = w >> 1, wn = w & 1;
  const int lr = l & 15, kg = l >> 4;
  const int swz = (lr & 7) * 8;                    // read-side XOR (elems)
  // staging geometry: issue = 256 lanes x 16B = 32 rows x 128B; 4 issues per operand
  const int r_l = tid >> 3;                        // 0..31
  const int ssrc = ((tid & 7) ^ (r_l & 7)) * 8;    // pre-swizzled source col (elems)
  const u16* gA = &A[(row0 + r_l) * (long)lda + ssrc];
  const u16* gB = &Bt[(col0 + r_l) * (long)ldb + ssrc];
  u16* const ldsA = smem + w * 512;                // wave-uniform bases (elems)
  u16* const ldsB = smem + 8192 + w * 512;
  const int NT = (kend - kbeg) >> 6;

  { // prologue: tile 0 -> dbuf 0
#pragma unroll
    for (int c = 0; c < 4; ++c) {
      GLOAD_LDS16(gA + (c * 32) * (long)lda + kbeg, ldsA + c * 2048);
      GLOAD_LDS16(gB + (c * 32) * (long)ldb + kbeg, ldsB + c * 2048);
    }
  }
  asm volatile("s_waitcnt vmcnt(0)" ::: "memory");
  __builtin_amdgcn_s_barrier();
  __builtin_amdgcn_sched_barrier(0);

  for (int t = 0; t < NT; ++t) {
    const int d = (t & 1) << 14;                   // dbuf offset (elems)
    const int dn = ((t + 1) & 1) << 14;
    const bool pf = (t + 1 < NT);
    const long k1 = kbeg + (long)(t + 1) * 64;
    bf16x8 af[4], bv[4];
    // ---- phase 0: stage A(t+1); compute k-step s=0 ----
    if (pf) {
#pragma unroll
      for (int c = 0; c < 4; ++c)
        GLOAD_LDS16(gA + (c * 32) * (long)lda + k1, ldsA + dn + c * 2048);
    }
#pragma unroll
    for (int i = 0; i < 4; ++i) {
      af[i] = *(const bf16x8*)&smem[d + (wm * 64 + i * 16 + lr) * 64 + (kg * 8 ^ swz)];
      bv[i] = *(const bf16x8*)&smem[d + 8192 + (wn * 64 + i * 16 + lr) * 64 + (kg * 8 ^ swz)];
    }
    __builtin_amdgcn_s_setprio(1);
#pragma unroll
    for (int mf = 0; mf < 4; ++mf)
#pragma unroll
      for (int nf = 0; nf < 4; ++nf)
        acc[mf][nf] = __builtin_amdgcn_mfma_f32_16x16x32_bf16(af[mf], bv[nf], acc[mf][nf], 0, 0, 0);
    __builtin_amdgcn_s_setprio(0);
    // ---- phase 1: stage B(t+1); compute k-step s=1 ----
    if (pf) {
#pragma unroll
      for (int c = 0; c < 4; ++c)
        GLOAD_LDS16(gB + (c * 32) * (long)ldb + k1, ldsB + dn + c * 2048);
    }
#pragma unroll
    for (int i = 0; i < 4; ++i) {
      af[i] = *(const bf16x8*)&smem[d + (wm * 64 + i * 16 + lr) * 64 + ((32 + kg * 8) ^ swz)];
      bv[i] = *(const bf16x8*)&smem[d + 8192 + (wn * 64 + i * 16 + lr) * 64 + ((32 + kg * 8) ^ swz)];
    }
    __builtin_amdgcn_s_setprio(1);
#pragma unroll
    for (int mf = 0; mf < 4; ++mf)
#pragma unroll
      for (int nf = 0; nf < 4; ++nf)
        acc[mf][nf] = __builtin_amdgcn_mfma_f32_16x16x32_bf16(af[mf], bv[nf], acc[mf][nf], 0, 0, 0);
    __builtin_amdgcn_s_setprio(0);
    asm volatile("s_waitcnt vmcnt(0)" ::: "memory");  // t+1 stage landed; mostly shadowed
    __builtin_amdgcn_s_barrier();
    __builtin_amdgcn_sched_barrier(0);
  }
}

#define EPI_VARS                                   \
  const int l = threadIdx.x & 63;                  \
  const int w = threadIdx.x >> 6;                  \
  const int wm = w >> 1, wn = w & 1;               \
  const int mrow = (l >> 4) * 4, ncol = l & 15;

// ---------------- QKV projection (input + context merged) ----------------
__global__ __launch_bounds__(256, 2) void k_gemm_qkv(
    const u16* __restrict__ XIN, const u16* __restrict__ XCTX,
    const u16* __restrict__ WQI, const u16* __restrict__ WQC,
    const float* __restrict__ bqi, const float* __restrict__ bqc,
    u16* __restrict__ qb, u16* __restrict__ kb, u16* __restrict__ vt) {
  __shared__ u16 smem[32768];
  f32x4 acc[4][4] = {};
  const bool isCtx = blockIdx.x >= 64;
  const u16* X = isCtx ? XCTX : XIN;
  const u16* W = isCtx ? WQC : WQI;
  const float* bias = isCtx ? bqc : bqi;
  const int seg_start = isCtx ? 0 : 512;
  long row0 = (long)(isCtx ? blockIdx.x - 64 : blockIdx.x) * 128;
  long col0 = (long)blockIdx.y * 128;
  gemm_bk64(X, W, 1024, 1024, row0, col0, 0, 1024, smem, acc);
  EPI_VARS
#pragma unroll
  for (int mf = 0; mf < 4; ++mf)
#pragma unroll
    for (int nf = 0; nf < 4; ++nf)
#pragma unroll
      for (int r = 0; r < 4; ++r) {
        int m = (int)row0 + wm * 64 + mf * 16 + mrow + r;
        int n = (int)col0 + wn * 64 + nf * 16 + ncol;
        float v = acc[mf][nf][r] + bias[n];
        int b, s;
        if (isCtx) { b = m >> 9; s = m & 511; } else { b = m >> 12; s = m & 4095; }
        long grow = (long)b * 4608 + seg_start + s;
        if (n < 1024)      qb[grow * 1024 + n] = f2bf(v);
        else if (n < 2048) kb[grow * 1024 + (n - 1024)] = f2bf(v);
        else               vt[((long)b * 1024 + (n - 2048)) * 4608 + seg_start + s] = f2bf(v);
      }
}

// ---------------- RMSNorm + RoPE (in-place on q_buf / k_buf) ----------------
__global__ __launch_bounds__(256) void k_normrope(u16* __restrict__ qb, u16* __restrict__ kb,
                                                  const float* __restrict__ qsi, const float* __restrict__ ksi,
                                                  const float* __restrict__ qsc, const float* __restrict__ ksc) {
  __shared__ float sm[4];
  const int row = blockIdx.x;    // 0..9215  (b*4608 + n)
  const int which = blockIdx.y;  // 0 = q, 1 = k
  const int n = row % 4608;
  u16* buf = which ? kb : qb;
  const float* scale = which ? (n < 512 ? ksc : ksi) : (n < 512 ? qsc : qsi);
  u16* rp = buf + (long)row * 1024;
  const int t = threadIdx.x;
  float x[4];
  int idx[4];
  float ss = 0.f;
#pragma unroll
  for (int i = 0; i < 2; ++i) {
    int p = t + i * 256;                 // pair index 0..511
    int h = p >> 5, j = p & 31;          // head, rot index
    int e1 = h * 64 + j;
    idx[2 * i] = e1; idx[2 * i + 1] = e1 + 32;
    float a = bf2f(rp[e1]), b = bf2f(rp[e1 + 32]);
    x[2 * i] = a; x[2 * i + 1] = b;
    ss += a * a + b * b;
  }
#pragma unroll
  for (int o = 32; o; o >>= 1) ss += __shfl_xor(ss, o, 64);
  if ((t & 63) == 0) sm[t >> 6] = ss;
  __syncthreads();
  ss = sm[0] + sm[1] + sm[2] + sm[3];
  const float rr = rsqrtf(ss * (1.0f / 1024.0f) + 1e-6f);
#pragma unroll
  for (int i = 0; i < 2; ++i) {
    int p = t + i * 256;
    int j = p & 31;
    float x1 = x[2 * i] * rr * scale[idx[2 * i]];
    float x2 = x[2 * i + 1] * rr * scale[idx[2 * i + 1]];
    float freq = exp2f((float)j * (-13.287712379549449f / 32.0f)); // 10000^(-j/32)
    float ang = (float)n * freq;
    float sn, cs;
    sincosf(ang, &sn, &cs);
    rp[idx[2 * i]]     = f2bf(x1 * cs - x2 * sn);
    rp[idx[2 * i + 1]] = f2bf(x2 * cs + x1 * sn);
  }
}

// ---------------- S = (Q @ K^T) * 0.125  (fp32 out) ----------------
__global__ __launch_bounds__(256, 2) void k_gemm_s(const u16* __restrict__ Q, const u16* __restrict__ Kb,
                                                   float* __restrict__ S) {
  __shared__ u16 smem[32768];
  f32x4 acc[4][4] = {};
  long row0 = (long)blockIdx.x * 128;
  long col0 = (long)blockIdx.y * 128;
  gemm_bk64(Q, Kb, 1024, 1024, row0, col0, 0, 1024, smem, acc);
  EPI_VARS
#pragma unroll
  for (int mf = 0; mf < 4; ++mf)
#pragma unroll
    for (int nf = 0; nf < 4; ++nf)
#pragma unroll
      for (int r = 0; r < 4; ++r) {
        long m = row0 + wm * 64 + mf * 16 + mrow + r;
        long n = col0 + wn * 64 + nf * 16 + ncol;
        S[m * 4608 + n] = acc[mf][nf][r] * 0.125f;
      }
}

// ---------------- row softmax: P = softmax(S row) as bf16 ----------------
__global__ __launch_bounds__(256) void k_softmax(const float* __restrict__ S, u16* __restrict__ P) {
  __shared__ float sm[4];
  const long row = blockIdx.x;
  const float* sr = S + row * 4608;
  const int t = threadIdx.x;
  float v[18];
  float mx = -3.4e38f;
#pragma unroll
  for (int i = 0; i < 18; ++i) { v[i] = sr[i * 256 + t]; mx = fmaxf(mx, v[i]); }
#pragma unroll
  for (int o = 32; o; o >>= 1) mx = fmaxf(mx, __shfl_xor(mx, o, 64));
  if ((t & 63) == 0) sm[t >> 6] = mx;
  __syncthreads();
  mx = fmaxf(fmaxf(sm[0], sm[1]), fmaxf(sm[2], sm[3]));
  __syncthreads();
  float sum = 0.f;
#pragma unroll
  for (int i = 0; i < 18; ++i) { v[i] = __expf(v[i] - mx); sum += v[i]; }
#pragma unroll
  for (int o = 32; o; o >>= 1) sum += __shfl_xor(sum, o, 64);
  if ((t & 63) == 0) sm[t >> 6] = sum;
  __syncthreads();
  sum = sm[0] + sm[1] + sm[2] + sm[3];
  const float inv = 1.0f / sum;
  u16* pr = P + row * 4608;
#pragma unroll
  for (int i = 0; i < 18; ++i) pr[i * 256 + t] = f2bf(v[i] * inv);
}

// ---------------- O partials = P @ V (split-K over z), fp32 out ----------------
__global__ __launch_bounds__(256, 2) void k_gemm_o(const u16* __restrict__ P, const u16* __restrict__ VT,
                                                   float* __restrict__ OP) {
  __shared__ u16 smem[32768];
  f32x4 acc[4][4] = {};
  long row0 = (long)blockIdx.x * 128;
  long col0 = (long)blockIdx.y * 128;
  const int kc = blockIdx.z;           // 0..3, K chunk of 1152 (=18 tiles of 64)
  gemm_bk64(P, VT, 4608, 4608, row0, col0, kc * 1152, (kc + 1) * 1152, smem, acc);
  float* op = OP + (long)kc * 4608 * 1024;
  EPI_VARS
#pragma unroll
  for (int mf = 0; mf < 4; ++mf)
#pragma unroll
    for (int nf = 0; nf < 4; ++nf)
#pragma unroll
      for (int r = 0; r < 4; ++r) {
        long m = row0 + wm * 64 + mf * 16 + mrow + r;
        long n = col0 + wn * 64 + nf * 16 + ncol;
        op[m * 1024 + n] = acc[mf][nf][r];
      }
}

// ---------------- reduce 4 fp32 partials -> bf16 AO ----------------
__global__ __launch_bounds__(256) void k_reduce4(const float* __restrict__ OP, u16* __restrict__ AO) {
  const long st = 4608L * 1024;
  long i = ((long)blockIdx.x * 256 + threadIdx.x) * 4;
  float4 a = *(const float4*)&OP[i];
  float4 b = *(const float4*)&OP[i + st];
  float4 c = *(const float4*)&OP[i + 2 * st];
  float4 d = *(const float4*)&OP[i + 3 * st];
  ushort4 o;
  o.x = f2bf(a.x + b.x + c.x + d.x);
  o.y = f2bf(a.y + b.y + c.y + d.y);
  o.z = f2bf(a.z + b.z + c.z + d.z);
  o.w = f2bf(a.w + b.w + c.w + d.w);
  *(ushort4*)&AO[i] = o;
}

// ---------------- merged output projections: out = AO @ W^T + b (fp32 out) ----------------
__global__ __launch_bounds__(256, 2) void k_gemm_out2(const u16* __restrict__ AO,
                                                      const u16* __restrict__ WOI, const u16* __restrict__ WOC,
                                                      const float* __restrict__ boi, const float* __restrict__ boc,
                                                      float* __restrict__ out) {
  __shared__ u16 smem[32768];
  f32x4 acc[4][4] = {};
  long row0 = (long)blockIdx.x * 128;      // global row in [0,9216)
  long col0 = (long)blockIdx.y * 128;
  int b = (int)(row0 / 4608);
  int s0 = (int)(row0 % 4608);
  const bool ctx = s0 < 512;               // 512 % 128 == 0 -> uniform per block
  const u16* W = ctx ? WOC : WOI;
  const float* bias = ctx ? boc : boi;
  float* ob = ctx ? out + 8388608 + ((long)b * 512 + s0) * 1024
                  : out + ((long)b * 4096 + (s0 - 512)) * 1024;
  gemm_bk64(AO, W, 1024, 1024, row0, col0, 0, 1024, smem, acc);
  EPI_VARS
#pragma unroll
  for (int mf = 0; mf < 4; ++mf)
#pragma unroll
    for (int nf = 0; nf < 4; ++nf)
#pragma unroll
      for (int r = 0; r < 4; ++r) {
        long m = wm * 64 + mf * 16 + mrow + r;        // local row within tile
        long n = col0 + wn * 64 + nf * 16 + ncol;
        ob[m * 1024 + n] = acc[mf][nf][r] + bias[n];
      }
}

// ---------------- launch ----------------
extern "C" void kernel_launch(void* const* d_in, const int* in_sizes, int n_in,
                              void* d_out, int out_size, void* d_ws, size_t ws_size,
                              hipStream_t stream) {
  const float* input   = (const float*)d_in[0];
  const float* context = (const float*)d_in[1];
  const float* Wqi     = (const float*)d_in[2];
  const float* bqi     = (const float*)d_in[3];
  const float* Wqc     = (const float*)d_in[4];
  const float* bqc     = (const float*)d_in[5];
  const float* qsi     = (const float*)d_in[6];
  const float* ksi     = (const float*)d_in[7];
  const float* qsc     = (const float*)d_in[8];
  const float* ksc     = (const float*)d_in[9];
  const float* Woi     = (const float*)d_in[10];
  const float* boi     = (const float*)d_in[11];
  const float* Woc     = (const float*)d_in[12];
  const float* boc     = (const float*)d_in[13];
  float* out = (float*)d_out;

  uint8_t* ws = (uint8_t*)d_ws;
  // workspace layout (bytes)
  u16* XIN  = (u16*)(ws + 0);            // 2*4096*1024 bf16       = 16,777,216
  u16* XCTX = (u16*)(ws + 16777216);     // 2*512*1024             =  2,097,152
  u16* WQI  = (u16*)(ws + 18874368);     // 3072*1024              =  6,291,456
  u16* WQC  = (u16*)(ws + 25165824);     // 3072*1024              =  6,291,456
  u16* WOI  = (u16*)(ws + 31457280);     // 1024*1024              =  2,097,152
  u16* WOC  = (u16*)(ws + 33554432);     // 1024*1024              =  2,097,152
  u16* QB   = (u16*)(ws + 35651584);     // 2*4608*1024            = 18,874,368
  u16* KB   = (u16*)(ws + 54525952);     // 2*4608*1024            = 18,874,368
  u16* VT   = (u16*)(ws + 73400320);     // 2*1024*4608            = 18,874,368
  u16* AO   = (u16*)(ws + 92274688);     // 2*4608*1024            = 18,874,368
  float* S32 = (float*)(ws + 111149056); // 4608*4608 fp32 (per-batch; also 4x fp32 O-partials) = 84,934,656
  u16* PB   = (u16*)(ws + 196083712);    // 4608*4608 bf16 (per-batch, reused) = 42,467,328
  // total = 238,551,040 bytes

  // fp32 -> bf16 conversions
  k_f32_to_bf16<<<dim3(8192), 256, 0, stream>>>(input, XIN, 2 * 4096 * 1024);
  k_f32_to_bf16<<<dim3(1024), 256, 0, stream>>>(context, XCTX, 2 * 512 * 1024);
  k_f32_to_bf16<<<dim3(3072), 256, 0, stream>>>(Wqi, WQI, 3072 * 1024);
  k_f32_to_bf16<<<dim3(3072), 256, 0, stream>>>(Wqc, WQC, 3072 * 1024);
  k_f32_to_bf16<<<dim3(1024), 256, 0, stream>>>(Woi, WOI, 1024 * 1024);
  k_f32_to_bf16<<<dim3(1024), 256, 0, stream>>>(Woc, WOC, 1024 * 1024);

  // QKV projections, input (blocks 0..63) + context (blocks 64..71) in one launch
  k_gemm_qkv<<<dim3(72, 24), 256, 0, stream>>>(XIN, XCTX, WQI, WQC, bqi, bqc, QB, KB, VT);

  // RMSNorm + RoPE in place on q,k
  k_normrope<<<dim3(9216, 2), 256, 0, stream>>>(QB, KB, qsi, ksi, qsc, ksc);

  // attention, one batch at a time (S/P buffers reused; O-partials alias S32)
  for (int b = 0; b < 2; ++b) {
    const u16* Qb  = QB + (long)b * 4608 * 1024;
    const u16* Kbp = KB + (long)b * 4608 * 1024;
    const u16* VTb = VT + (long)b * 1024 * 4608;
    u16* AOb = AO + (long)b * 4608 * 1024;
    k_gemm_s<<<dim3(36, 36), 256, 0, stream>>>(Qb, Kbp, S32);
    k_softmax<<<dim3(4608), 256, 0, stream>>>(S32, PB);
    k_gemm_o<<<dim3(36, 8, 4), 256, 0, stream>>>(PB, VTb, (float*)S32);
    k_reduce4<<<dim3(4608), 256, 0, stream>>>((const float*)S32, AOb);
  }

  // merged output projections
  k_gemm_out2<<<dim3(72, 8), 256, 0, stream>>>(AO, WOI, WOC, boi, boc, out);
}